// Round 3
// baseline (1038.796 us; speedup 1.0000x reference)
//
#include <hip/hip_runtime.h>
#include <hip/hip_bf16.h>
#include <hip/hip_cooperative_groups.h>
#include <cstdint>
#include <cstddef>

namespace cg = cooperative_groups;

#define BB 32
#define LL 2048
#define DD 1024
#define HH 16
#define HDIM 64
#define NL 4
#define NCHUNK 8
#define CHUNK 256
#define NEGINF -1e30f
#define KS 16
#define KLEN 64

typedef __attribute__((ext_vector_type(8))) short bf16x8;
typedef __attribute__((ext_vector_type(4))) float f32x4;

__device__ __forceinline__ unsigned short f2b(float x) {
    union { float f; unsigned int u; } v; v.f = x;
    unsigned int r = (v.u + 0x7FFFu + ((v.u >> 16) & 1u)) >> 16;
    return (unsigned short)r;
}

// shared gemv tail: Xs[32][64] @ W[e0:e0+64, ct*64:+64] -> partials outp[ks][b][c]
__device__ __forceinline__ void gemv_tail(const float* __restrict__ W,
        float (*Xs)[KLEN], float* __restrict__ outp, int ct, int ks, int tid) {
    int e0 = ks * KLEN;
    int col = tid & 63, bg = tid >> 6;
    int c = ct * 64 + col;
    float acc[8] = {0.f, 0.f, 0.f, 0.f, 0.f, 0.f, 0.f, 0.f};
    for (int k = 0; k < KLEN; k += 4) {
        float w0 = W[(size_t)(e0 + k) * DD + c];
        float w1 = W[(size_t)(e0 + k + 1) * DD + c];
        float w2 = W[(size_t)(e0 + k + 2) * DD + c];
        float w3 = W[(size_t)(e0 + k + 3) * DD + c];
#pragma unroll
        for (int bb = 0; bb < 8; ++bb) {
            const float4 xv = *(const float4*)&Xs[bg * 8 + bb][k];
            acc[bb] += xv.x * w0 + xv.y * w1 + xv.z * w2 + xv.w * w3;
        }
    }
#pragma unroll
    for (int bb = 0; bb < 8; ++bb)
        outp[((size_t)(ks * BB) + bg * 8 + bb) * DD + c] = acc[bb];
}

// wk phase body (128 logical blocks of 256 thr): wk16[b,h,e] = Wk_h . qh_h (bf16), sbuf
__device__ __forceinline__ void wk_body(const float* __restrict__ qh,
        const float* __restrict__ Wk, const float* __restrict__ bk,
        unsigned short* __restrict__ wk16, float* __restrict__ sb,
        float (*qs)[HDIM + 1], int bid, int tid) {
    int h = bid >> 3, et = bid & 7;
    for (int i = tid; i < BB * HDIM; i += 256) {
        int bb = i >> 6, d = i & 63;
        qs[bb][d] = qh[bb * DD + h * HDIM + d];
    }
    __syncthreads();
    int b = tid & 31, eo = tid >> 5;
    for (int k = 0; k < 16; ++k) {
        int e = et * 128 + eo * 16 + k;
        const float* wrow = Wk + (size_t)e * DD + h * HDIM;
        float acc = 0.f;
#pragma unroll
        for (int d = 0; d < HDIM; ++d) acc += qs[b][d] * wrow[d];
        wk16[((size_t)(b * HH + h)) * DD + e] = f2b(acc);
    }
    if (et == 0 && tid < BB) {
        float acc = 0.f;
#pragma unroll
        for (int d = 0; d < HDIM; ++d) acc += qs[tid][d] * bk[h * HDIM + d];
        sb[tid * HH + h] = acc;
    }
}

// ---------------- cooperative prologue: qh = qt@Wq0 + bq0 ; wk16 for layer 0
__global__ __launch_bounds__(256) void k_pro(const float* __restrict__ qt,
        const float* __restrict__ Wq, const float* __restrict__ bq,
        const float* __restrict__ Wk, const float* __restrict__ bk,
        float* __restrict__ qp, float* __restrict__ qh,
        unsigned short* __restrict__ wk16, float* __restrict__ sbuf) {
    cg::grid_group grid = cg::this_grid();
    int bid = blockIdx.x, tid = threadIdx.x;
    __shared__ float Xv[KLEN];
    __shared__ float qs[BB][HDIM + 1];
    {
        int ct = bid & 15, ks = bid >> 4;
        int e0 = ks * KLEN;
        if (tid < KLEN) Xv[tid] = qt[e0 + tid];
        __syncthreads();
        int col = tid & 63, bg = tid >> 6;
        int c = ct * 64 + col;
        float acc = 0.f;
#pragma unroll 4
        for (int k = 0; k < KLEN; ++k) acc += Xv[k] * Wq[(size_t)(e0 + k) * DD + c];
#pragma unroll
        for (int j = 0; j < 8; ++j)
            qp[((size_t)(ks * BB) + bg * 8 + j) * DD + c] = acc;
    }
    grid.sync();
    if (bid < 128) {
        int i = bid * 256 + tid;
        int b = i >> 10, c = i & (DD - 1);
        float v = bq[c];
#pragma unroll
        for (int ks = 0; ks < KS; ++ks)
            v += qp[((size_t)(ks * BB) + b) * DD + c];
        qh[i] = v;
    }
    grid.sync();
    if (bid < 128) wk_body(qh, Wk, bk, wk16, sbuf, qs, bid, tid);
}

// ---------------- cooperative per-layer epilogue
__global__ __launch_bounds__(256) void k_epi(
        const float* __restrict__ ctx_p, const float* __restrict__ m_p,
        const float* __restrict__ s_p,
        const float* __restrict__ Wv, const float* __restrict__ bv,
        const float* __restrict__ Wo, const float* __restrict__ bo,
        const float* __restrict__ gamma, const float* __restrict__ beta,
        const float* __restrict__ Wqn, const float* __restrict__ bqn,
        const float* __restrict__ Wkn, const float* __restrict__ bkn,
        float* __restrict__ pvp, float* __restrict__ op,
        float* __restrict__ oraw, float* __restrict__ stats,
        float* __restrict__ qp, float* __restrict__ qh,
        unsigned short* __restrict__ wk16, float* __restrict__ sbuf,
        float* __restrict__ outp, int last) {
    cg::grid_group grid = cg::this_grid();
    int bid = blockIdx.x, tid = threadIdx.x;
    int ct = bid & 15, ks = bid >> 4;
    int e0 = ks * KLEN;
    __shared__ float Xs[BB][KLEN];
    __shared__ float wgtS[BB][NCHUNK];
    __shared__ float mgS[BB], SgS[BB];
    __shared__ float qs[BB][HDIM + 1];
    __shared__ float r1[4], r2[4];

    // P1: pv partials = (chunk-combined ctx for head ct) @ Wv
    {
        if (tid < BB) {
            int b = tid; float m = NEGINF;
            for (int c8 = 0; c8 < NCHUNK; ++c8)
                m = fmaxf(m, m_p[(b * NCHUNK + c8) * HH + ct]);
            float S = 0.f;
            for (int c8 = 0; c8 < NCHUNK; ++c8)
                S += s_p[(b * NCHUNK + c8) * HH + ct] *
                     __expf(m_p[(b * NCHUNK + c8) * HH + ct] - m);
            mgS[b] = m; SgS[b] = S;
        }
        __syncthreads();
        {
            int b = tid >> 3, c8 = tid & 7;
            wgtS[b][c8] = __expf(m_p[(b * NCHUNK + c8) * HH + ct] - mgS[b]) / SgS[b];
        }
        __syncthreads();
#pragma unroll
        for (int j = 0; j < 8; ++j) {
            int i = tid + j * 256;
            int b = i >> 6, k = i & 63;
            float x = 0.f;
#pragma unroll
            for (int c8 = 0; c8 < NCHUNK; ++c8)
                x += wgtS[b][c8] *
                     ctx_p[(((size_t)(b * NCHUNK + c8)) * HH + ct) * DD + e0 + k];
            Xs[b][k] = x;
        }
        __syncthreads();
        gemv_tail(Wv, Xs, pvp, ct, ks, tid);
    }
    grid.sync();
    // P2: o partials = (sum pv + bv) @ Wo
    {
#pragma unroll
        for (int j = 0; j < 8; ++j) {
            int i = tid + j * 256;
            int b = i >> 6, k = i & 63;
            float x = bv[e0 + k];
#pragma unroll
            for (int j2 = 0; j2 < KS; ++j2)
                x += pvp[((size_t)(j2 * BB) + b) * DD + e0 + k];
            Xs[b][k] = x;
        }
        __syncthreads();
        gemv_tail(Wo, Xs, op, ct, ks, tid);
    }
    grid.sync();
    // P3: combine + bo -> oraw, LN stats (32 blocks)
    if (bid < 32) {
        int b = bid;
        float s1 = 0.f, s2 = 0.f;
#pragma unroll
        for (int j = 0; j < 4; ++j) {
            int c = tid + j * 256;
            float v = bo[c];
#pragma unroll
            for (int k2 = 0; k2 < KS; ++k2)
                v += op[((size_t)(k2 * BB) + b) * DD + c];
            oraw[(size_t)b * DD + c] = v;
            s1 += v; s2 += v * v;
        }
#pragma unroll
        for (int off = 32; off; off >>= 1) {
            s1 += __shfl_xor(s1, off);
            s2 += __shfl_xor(s2, off);
        }
        int w = tid >> 6;
        if ((tid & 63) == 0) { r1[w] = s1; r2[w] = s2; }
        __syncthreads();
        if (tid == 0) {
            float a = r1[0] + r1[1] + r1[2] + r1[3];
            float q = r2[0] + r2[1] + r2[2] + r2[3];
            float mu = a / (float)DD, var = q / (float)DD - mu * mu;
            stats[b * 2] = mu;
            stats[b * 2 + 1] = rsqrtf(var + 1e-5f);
        }
    }
    grid.sync();
    if (last) {
        if (bid < 128) {
            int i = bid * 256 + tid;
            int b = i >> 10, c = i & (DD - 1);
            outp[i] = (oraw[i] - stats[b * 2]) * stats[b * 2 + 1] * gamma[c] + beta[c];
        }
        return;
    }
    // P4: q partials = LN(oraw) @ Wq_next
    {
#pragma unroll
        for (int j = 0; j < 8; ++j) {
            int i = tid + j * 256;
            int b = i >> 6, k = i & 63;
            float mu = stats[b * 2], rs = stats[b * 2 + 1];
            float x = (oraw[(size_t)b * DD + e0 + k] - mu) * rs * gamma[e0 + k] + beta[e0 + k];
            Xs[b][k] = x;
        }
        __syncthreads();
        gemv_tail(Wqn, Xs, qp, ct, ks, tid);
    }
    grid.sync();
    // P5: qh = sum partials + bq_next
    if (bid < 128) {
        int i = bid * 256 + tid;
        int b = i >> 10, c = i & (DD - 1);
        float v = bqn[c];
#pragma unroll
        for (int k2 = 0; k2 < KS; ++k2)
            v += qp[((size_t)(k2 * BB) + b) * DD + c];
        qh[i] = v;
    }
    grid.sync();
    // P6: wk16/sbuf for next layer
    if (bid < 128) wk_body(qh, Wkn, bkn, wk16, sbuf, qs, bid, tid);
}

// ---------------- main streaming attention pass (partial per (b, chunk))
// MODE 0: fp32 reads. MODE 1: fp32 reads + bf16 cache write. MODE 2: bf16 cache reads.
template<int MODE>
__global__ __launch_bounds__(1024) void k_attn(const float* __restrict__ toks,
        unsigned short* __restrict__ tcache,
        const int* __restrict__ lens, const unsigned short* __restrict__ wk16,
        const float* __restrict__ sb, float* __restrict__ ctx_p,
        float* __restrict__ m_p, float* __restrict__ s_p) {
    int b = blockIdx.x >> 3, chunk = blockIdx.x & 7;
    int tid = threadIdx.x, lane = tid & 63, w = tid >> 6;
    int len = lens[b];
    int base = chunk * CHUNK;
    int pidx = (b * NCHUNK + chunk) * HH;
    if (base >= len) {
        if (tid < HH) { m_p[pidx + tid] = NEGINF; s_p[pidx + tid] = 0.f; }
        return;
    }
    int nv = min(CHUNK, len - base);

    __shared__ __align__(16) unsigned short Tr[32][1032];  // row-major [t][e]
    __shared__ float Sred[16][HH][34];
    __shared__ unsigned short Pt[HH][40];
    __shared__ float sm_m[HH], sm_s[HH], sm_c[HH];

    if (tid < HH) { sm_m[tid] = NEGINF; sm_s[tid] = 0.f; }

    int hq = lane & 15, qg = lane >> 4;
    const unsigned short* wkb = wk16 + ((size_t)(b * HH + hq)) * DD + w * 64 + 8 * qg;
    bf16x8 afr0 = *(const bf16x8*)(wkb);
    bf16x8 afr1 = *(const bf16x8*)(wkb + 32);
    f32x4 zer = {0.f, 0.f, 0.f, 0.f};
    f32x4 ctxacc[4] = {zer, zer, zer, zer};
    float sbh = (tid < 512) ? sb[b * HH + (tid >> 5)] : 0.f;
    int st = tid >> 7;           // staging token within pass
    int se = (tid & 127) * 8;    // staging e offset
    __syncthreads();

    for (int g = 0; g < 8; ++g) {
        int t0 = g * 32;
        if (t0 >= nv) break;
        if (MODE == 2) {
            const unsigned short* srcr = tcache + ((size_t)(b * LL + base + t0)) * DD;
#pragma unroll
            for (int p = 0; p < 4; ++p) {
                int t = p * 8 + st;
                bf16x8 v = *(const bf16x8*)(srcr + (size_t)t * DD + se);
                *(bf16x8*)&Tr[t][se] = v;
            }
        } else {
            const float* srcr = toks + ((size_t)(b * LL + base + t0)) * DD;
#pragma unroll
            for (int p = 0; p < 4; ++p) {
                int t = p * 8 + st;
                const float* sp = srcr + (size_t)t * DD + se;
                float4 a0 = *(const float4*)sp;
                float4 a1 = *(const float4*)(sp + 4);
                bf16x8 v;
                v[0] = f2b(a0.x); v[1] = f2b(a0.y); v[2] = f2b(a0.z); v[3] = f2b(a0.w);
                v[4] = f2b(a1.x); v[5] = f2b(a1.y); v[6] = f2b(a1.z); v[7] = f2b(a1.w);
                *(bf16x8*)&Tr[t][se] = v;
                if (MODE == 1)
                    *(bf16x8*)(tcache + ((size_t)(b * LL + base + t0 + t)) * DD + se) = v;
            }
        }
        __syncthreads();
        f32x4 s0 = zer, s1 = zer;
        {
            int eb = w * 64 + 8 * qg;
            s0 = __builtin_amdgcn_mfma_f32_16x16x32_bf16(afr0, *(const bf16x8*)&Tr[hq][eb], s0, 0, 0, 0);
            s0 = __builtin_amdgcn_mfma_f32_16x16x32_bf16(afr1, *(const bf16x8*)&Tr[hq][eb + 32], s0, 0, 0, 0);
            s1 = __builtin_amdgcn_mfma_f32_16x16x32_bf16(afr0, *(const bf16x8*)&Tr[16 + hq][eb], s1, 0, 0, 0);
            s1 = __builtin_amdgcn_mfma_f32_16x16x32_bf16(afr1, *(const bf16x8*)&Tr[16 + hq][eb + 32], s1, 0, 0, 0);
        }
#pragma unroll
        for (int r = 0; r < 4; ++r) {
            Sred[w][qg * 4 + r][hq] = s0[r];
            Sred[w][qg * 4 + r][16 + hq] = s1[r];
        }
        __syncthreads();
        if (tid < 512) {
            int h = tid >> 5, t = tid & 31;
            float s = 0.f;
#pragma unroll
            for (int ww = 0; ww < 16; ++ww) s += Sred[ww][h][t];
            s = (s + sbh) * 0.125f;
            bool valid = (t0 + t) < nv;
            if (!valid) s = NEGINF;
            float tm = s;
#pragma unroll
            for (int off = 16; off; off >>= 1) tm = fmaxf(tm, __shfl_xor(tm, off, 32));
            float oldm = sm_m[h];
            float newm = fmaxf(oldm, tm);
            float pv = valid ? __expf(s - newm) : 0.f;
            float ps = pv;
#pragma unroll
            for (int off = 16; off; off >>= 1) ps += __shfl_xor(ps, off, 32);
            if (t == 0) {
                float corr = __expf(oldm - newm);
                sm_c[h] = corr;
                sm_m[h] = newm;
                sm_s[h] = sm_s[h] * corr + ps;
            }
            Pt[h][t] = f2b(pv);
        }
        __syncthreads();
        {
            float cr[4];
#pragma unroll
            for (int r = 0; r < 4; ++r) cr[r] = sm_c[qg * 4 + r];
            bf16x8 pafr;
            ushort4 pa0 = *(const ushort4*)&Pt[hq][8 * qg];
            ushort4 pa1 = *(const ushort4*)&Pt[hq][8 * qg + 4];
            pafr[0] = pa0.x; pafr[1] = pa0.y; pafr[2] = pa0.z; pafr[3] = pa0.w;
            pafr[4] = pa1.x; pafr[5] = pa1.y; pafr[6] = pa1.z; pafr[7] = pa1.w;
#pragma unroll
            for (int et = 0; et < 4; ++et) {
#pragma unroll
                for (int r = 0; r < 4; ++r) ctxacc[et][r] *= cr[r];
                bf16x8 bfr;
                int ec = w * 64 + et * 16 + hq;
#pragma unroll
                for (int i = 0; i < 8; ++i) bfr[i] = (short)Tr[8 * qg + i][ec];
                ctxacc[et] = __builtin_amdgcn_mfma_f32_16x16x32_bf16(pafr, bfr, ctxacc[et], 0, 0, 0);
            }
        }
        __syncthreads();
    }
    if (tid < HH) { m_p[pidx + tid] = sm_m[tid]; s_p[pidx + tid] = sm_s[tid]; }
#pragma unroll
    for (int et = 0; et < 4; ++et)
#pragma unroll
        for (int r = 0; r < 4; ++r) {
            int h = qg * 4 + r, e = w * 64 + et * 16 + hq;
            ctx_p[((size_t)pidx + h) * DD + e] = ctxacc[et][r];
        }
}

extern "C" void kernel_launch(void* const* d_in, const int* in_sizes, int n_in,
                              void* d_out, int out_size, void* d_ws, size_t ws_size,
                              hipStream_t stream) {
    const float* toks  = (const float*)d_in[0];
    const int*   lens  = (const int*)d_in[1];
    const float* qt    = (const float*)d_in[2];
    const float* Wq    = (const float*)d_in[3];
    const float* bq    = (const float*)d_in[4];
    const float* Wk    = (const float*)d_in[5];
    const float* bk    = (const float*)d_in[6];
    const float* Wv    = (const float*)d_in[7];
    const float* bv    = (const float*)d_in[8];
    const float* Wo    = (const float*)d_in[9];
    const float* bo    = (const float*)d_in[10];
    const float* gamma = (const float*)d_in[11];
    const float* beta  = (const float*)d_in[12];
    float* out = (float*)d_out;
    float* ws  = (float*)d_ws;

    float* ctx_p = ws;                       // 4194304
    float* m_p   = ws + 4194304;             // 4096
    float* s_p   = ws + 4198400;             // 4096
    float* pvp   = ws + 4202496;             // 524288
    float* op    = ws + 4726784;             // 524288
    float* oraw  = ws + 5251072;             // 32768
    float* stats = ws + 5283840;             // 64
    float* qp    = ws + 5283904;             // 524288
    float* qh    = ws + 5808192;             // 32768
    float* sbuf  = ws + 5840960;             // 512
    unsigned short* wk16 = (unsigned short*)(ws + 5841472);
    const size_t base_floats = 6103616;
    unsigned short* tcache = (unsigned short*)(ws + base_floats);
    const size_t need_cache = base_floats * 4 + (size_t)BB * LL * DD * 2;
    const bool use_cache = (ws_size >= need_cache);

    {
        const float* Wq0 = Wq; const float* bq0 = bq;
        const float* Wk0 = Wk; const float* bk0 = bk;
        void* args[] = { (void*)&qt, (void*)&Wq0, (void*)&bq0, (void*)&Wk0,
                         (void*)&bk0, (void*)&qp, (void*)&qh, (void*)&wk16,
                         (void*)&sbuf };
        hipLaunchCooperativeKernel((void*)k_pro, dim3(256), dim3(256), args, 0, stream);
    }

    for (int i = 0; i < NL; ++i) {
        if (use_cache) {
            if (i == 0)
                k_attn<1><<<256, 1024, 0, stream>>>(toks, tcache, lens, wk16,
                        sbuf, ctx_p, m_p, s_p);
            else
                k_attn<2><<<256, 1024, 0, stream>>>(toks, tcache, lens, wk16,
                        sbuf, ctx_p, m_p, s_p);
        } else {
            k_attn<0><<<256, 1024, 0, stream>>>(toks, tcache, lens, wk16,
                    sbuf, ctx_p, m_p, s_p);
        }
        int last = (i == NL - 1);
        const float* Wv_i = Wv + (size_t)i * DD * DD;
        const float* bv_i = bv + i * DD;
        const float* Wo_i = Wo + (size_t)i * DD * DD;
        const float* bo_i = bo + i * DD;
        const float* ga_i = gamma + i * DD;
        const float* be_i = beta + i * DD;
        const float* Wqn = last ? Wq : (Wq + (size_t)(i + 1) * DD * DD);
        const float* bqn = last ? bq : (bq + (i + 1) * DD);
        const float* Wkn = last ? Wk : (Wk + (size_t)(i + 1) * DD * DD);
        const float* bkn = last ? bk : (bk + (i + 1) * DD);
        const float* ctx_c = ctx_p; const float* m_c = m_p; const float* s_c = s_p;
        void* args[] = { (void*)&ctx_c, (void*)&m_c, (void*)&s_c,
                         (void*)&Wv_i, (void*)&bv_i, (void*)&Wo_i, (void*)&bo_i,
                         (void*)&ga_i, (void*)&be_i,
                         (void*)&Wqn, (void*)&bqn, (void*)&Wkn, (void*)&bkn,
                         (void*)&pvp, (void*)&op, (void*)&oraw, (void*)&stats,
                         (void*)&qp, (void*)&qh, (void*)&wk16, (void*)&sbuf,
                         (void*)&out, (void*)&last };
        hipLaunchCooperativeKernel((void*)k_epi, dim3(256), dim3(256), args, 0, stream);
    }
}

// Round 4
// 349.184 us; speedup vs baseline: 2.9749x; 2.9749x over previous
//
#include <hip/hip_runtime.h>
#include <hip/hip_bf16.h>
#include <cstdint>
#include <cstddef>

#define BB 32
#define LL 2048
#define DD 1024
#define HH 16
#define HDIM 64
#define NL 4
#define NCHUNK 8
#define CHUNK 256
#define NEGINF -1e30f
#define KS 32          // K-splits for GEMVs
#define KLEN 32        // 1024 / KS

typedef __attribute__((ext_vector_type(8))) short bf16x8;
typedef __attribute__((ext_vector_type(4))) float f32x4;

__device__ __forceinline__ unsigned short f2b(float x) {
    union { float f; unsigned int u; } v; v.f = x;
    unsigned int r = (v.u + 0x7FFFu + ((v.u >> 16) & 1u)) >> 16;
    return (unsigned short)r;
}

// ---------------- g0[b][c] = qt[c]
__global__ __launch_bounds__(256) void k_bcast(const float* __restrict__ qt,
        float* __restrict__ g0) {
    int i = blockIdx.x * 256 + threadIdx.x;
    g0[i] = qt[i & (DD - 1)];
}

// ---------------- split-K GEMV partials: part[ks][b][c] = X[b, ks*32:+32] @ W[.., c]
// SRC 0: X = Xg (plain [32][1024])
// SRC 1: X = (Xg - mu)*rstd*gamma + beta
// SRC 2: X = bias + sum_ks' parts_in
// SRC 3: X = sum_c8 wgt[b][c8]*ctx_p[...]   (head = col-tile ct)
template<int SRC>
__global__ __launch_bounds__(256) void k_gemv(
        const float* __restrict__ Xg,
        const float* __restrict__ stats, const float* __restrict__ gamma,
        const float* __restrict__ beta,
        const float* __restrict__ parts_in, const float* __restrict__ bias_in,
        const float* __restrict__ ctx_p, const float* __restrict__ m_p,
        const float* __restrict__ s_p,
        const float* __restrict__ W, float* __restrict__ outp) {
    int bid = blockIdx.x, tid = threadIdx.x;
    int ct = bid & 15, ks = bid >> 4;   // ct: 16 col-tiles, ks: 32 K-splits
    int e0 = ks * KLEN;
    __shared__ float Xs[BB][KLEN];
    __shared__ float wgtS[BB][NCHUNK];
    __shared__ float mgS[BB], SgS[BB];
    if (SRC == 3) {
        if (tid < BB) {
            int b = tid; float m = NEGINF;
            for (int c8 = 0; c8 < NCHUNK; ++c8)
                m = fmaxf(m, m_p[(b * NCHUNK + c8) * HH + ct]);
            float S = 0.f;
            for (int c8 = 0; c8 < NCHUNK; ++c8)
                S += s_p[(b * NCHUNK + c8) * HH + ct] *
                     __expf(m_p[(b * NCHUNK + c8) * HH + ct] - m);
            mgS[b] = m; SgS[b] = S;
        }
        __syncthreads();
        {
            int b = tid >> 3, c8 = tid & 7;
            wgtS[b][c8] = __expf(m_p[(b * NCHUNK + c8) * HH + ct] - mgS[b]) / SgS[b];
        }
        __syncthreads();
    }
    // stage Xs[32][32] (1024 elems, 4 per thread)
#pragma unroll
    for (int j = 0; j < 4; ++j) {
        int i = tid + j * 256;
        int b = i >> 5, k = i & 31;
        float x;
        if (SRC == 0) {
            x = Xg[(size_t)b * DD + e0 + k];
        } else if (SRC == 1) {
            float mu = stats[b * 2], rstd = stats[b * 2 + 1];
            x = (Xg[(size_t)b * DD + e0 + k] - mu) * rstd * gamma[e0 + k] + beta[e0 + k];
        } else if (SRC == 2) {
            x = bias_in[e0 + k];
#pragma unroll
            for (int j2 = 0; j2 < KS; ++j2)
                x += parts_in[((size_t)(j2 * BB) + b) * DD + e0 + k];
        } else {
            x = 0.f;
#pragma unroll
            for (int c8 = 0; c8 < NCHUNK; ++c8)
                x += wgtS[b][c8] *
                     ctx_p[(((size_t)(b * NCHUNK + c8)) * HH + ct) * DD + e0 + k];
        }
        Xs[b][k] = x;
    }
    __syncthreads();
    int col = tid & 63, bg = tid >> 6;
    int c = ct * 64 + col;
    float acc[8] = {0.f, 0.f, 0.f, 0.f, 0.f, 0.f, 0.f, 0.f};
    for (int k = 0; k < KLEN; k += 4) {
        float w0 = W[(size_t)(e0 + k) * DD + c];
        float w1 = W[(size_t)(e0 + k + 1) * DD + c];
        float w2 = W[(size_t)(e0 + k + 2) * DD + c];
        float w3 = W[(size_t)(e0 + k + 3) * DD + c];
#pragma unroll
        for (int bb = 0; bb < 8; ++bb) {
            const float4 xv = *(const float4*)&Xs[bg * 8 + bb][k];
            acc[bb] += xv.x * w0 + xv.y * w1 + xv.z * w2 + xv.w * w3;
        }
    }
#pragma unroll
    for (int bb = 0; bb < 8; ++bb)
        outp[((size_t)(ks * BB) + bg * 8 + bb) * DD + c] = acc[bb];
}

// ---------------- combine partials + bias -> Y[32][1024]
__global__ __launch_bounds__(256) void k_comb_bias(const float* __restrict__ parts,
        const float* __restrict__ bias, float* __restrict__ Y) {
    int i = blockIdx.x * 256 + threadIdx.x;
    int b = i >> 10, c = i & (DD - 1);
    float v = bias[c];
#pragma unroll
    for (int ks = 0; ks < KS; ++ks)
        v += parts[((size_t)(ks * BB) + b) * DD + c];
    Y[i] = v;
}

// ---------------- combine partials + bias -> oraw + LN stats
__global__ __launch_bounds__(256) void k_stats(const float* __restrict__ parts,
        const float* __restrict__ bo, float* __restrict__ oraw,
        float* __restrict__ stats) {
    int b = blockIdx.x, tid = threadIdx.x;
    float s1 = 0.f, s2 = 0.f;
#pragma unroll
    for (int j = 0; j < 4; ++j) {
        int c = tid + j * 256;
        float v = bo[c];
#pragma unroll
        for (int ks = 0; ks < KS; ++ks)
            v += parts[((size_t)(ks * BB) + b) * DD + c];
        oraw[(size_t)b * DD + c] = v;
        s1 += v; s2 += v * v;
    }
#pragma unroll
    for (int off = 32; off; off >>= 1) {
        s1 += __shfl_xor(s1, off);
        s2 += __shfl_xor(s2, off);
    }
    __shared__ float r1[4], r2[4];
    int w = tid >> 6;
    if ((tid & 63) == 0) { r1[w] = s1; r2[w] = s2; }
    __syncthreads();
    if (tid == 0) {
        float a = r1[0] + r1[1] + r1[2] + r1[3];
        float q = r2[0] + r2[1] + r2[2] + r2[3];
        float mu = a / (float)DD, var = q / (float)DD - mu * mu;
        stats[b * 2] = mu;
        stats[b * 2 + 1] = rsqrtf(var + 1e-5f);
    }
}

// ---------------- final LN apply
__global__ __launch_bounds__(256) void k_final(const float* __restrict__ oraw,
        const float* __restrict__ stats, const float* __restrict__ gamma,
        const float* __restrict__ beta, float* __restrict__ outp) {
    int i = blockIdx.x * 256 + threadIdx.x;
    int b = i >> 10, c = i & (DD - 1);
    outp[i] = (oraw[i] - stats[b * 2]) * stats[b * 2 + 1] * gamma[c] + beta[c];
}

// ---------------- wk[b,h,e] = Wk[e, h*64:+64] . qh[b, h*64:+64] (bf16) + sbuf
// grid 256: h(16) x et(16), each et covers 64 e's
__global__ __launch_bounds__(256) void k_wk(const float* __restrict__ qh,
        const float* __restrict__ Wk, const float* __restrict__ bk,
        unsigned short* __restrict__ wk16, float* __restrict__ sb) {
    int h = blockIdx.x >> 4, et = blockIdx.x & 15;
    int tid = threadIdx.x;
    __shared__ float qs[BB][HDIM + 1];
    for (int i = tid; i < BB * HDIM; i += 256) {
        int bb = i >> 6, d = i & 63;
        qs[bb][d] = qh[bb * DD + h * HDIM + d];
    }
    __syncthreads();
    int b = tid & 31, eo = tid >> 5;   // eo: 0..7
    for (int k = 0; k < 8; ++k) {
        int e = et * 64 + eo * 8 + k;
        const float* wrow = Wk + (size_t)e * DD + h * HDIM;
        float acc = 0.f;
#pragma unroll
        for (int d = 0; d < HDIM; ++d) acc += qs[b][d] * wrow[d];
        wk16[((size_t)(b * HH + h)) * DD + e] = f2b(acc);
    }
    if (et == 0 && tid < BB) {
        float acc = 0.f;
#pragma unroll
        for (int d = 0; d < HDIM; ++d) acc += qs[tid][d] * bk[h * HDIM + d];
        sb[tid * HH + h] = acc;
    }
}

// ---------------- main streaming attention pass (partial per (b, chunk))
// MODE 0: fp32 reads. MODE 1: fp32 reads + bf16 cache write. MODE 2: bf16 cache reads.
template<int MODE>
__global__ __launch_bounds__(1024) void k_attn(const float* __restrict__ toks,
        unsigned short* __restrict__ tcache,
        const int* __restrict__ lens, const unsigned short* __restrict__ wk16,
        const float* __restrict__ sb, float* __restrict__ ctx_p,
        float* __restrict__ m_p, float* __restrict__ s_p) {
    int b = blockIdx.x >> 3, chunk = blockIdx.x & 7;
    int tid = threadIdx.x, lane = tid & 63, w = tid >> 6;
    int len = lens[b];
    int base = chunk * CHUNK;
    int pidx = (b * NCHUNK + chunk) * HH;
    if (base >= len) {
        if (tid < HH) { m_p[pidx + tid] = NEGINF; s_p[pidx + tid] = 0.f; }
        return;
    }
    int nv = min(CHUNK, len - base);

    __shared__ __align__(16) unsigned short Tr[32][1032];  // row-major [t][e]
    __shared__ float Sred[16][HH][34];
    __shared__ unsigned short Pt[HH][40];
    __shared__ float sm_m[HH], sm_s[HH], sm_c[HH];

    if (tid < HH) { sm_m[tid] = NEGINF; sm_s[tid] = 0.f; }

    int hq = lane & 15, qg = lane >> 4;
    const unsigned short* wkb = wk16 + ((size_t)(b * HH + hq)) * DD + w * 64 + 8 * qg;
    bf16x8 afr0 = *(const bf16x8*)(wkb);
    bf16x8 afr1 = *(const bf16x8*)(wkb + 32);
    f32x4 zer = {0.f, 0.f, 0.f, 0.f};
    f32x4 ctxacc[4] = {zer, zer, zer, zer};
    float sbh = (tid < 512) ? sb[b * HH + (tid >> 5)] : 0.f;
    int st = tid >> 7;           // staging token within pass (0..7)
    int se = (tid & 127) * 8;    // staging e offset
    __syncthreads();

    for (int g = 0; g < 8; ++g) {
        int t0 = g * 32;
        if (t0 >= nv) break;
        if (MODE == 2) {
            const unsigned short* srcr = tcache + ((size_t)(b * LL + base + t0)) * DD;
#pragma unroll
            for (int p = 0; p < 4; ++p) {
                int t = p * 8 + st;
                bf16x8 v = *(const bf16x8*)(srcr + (size_t)t * DD + se);
                *(bf16x8*)&Tr[t][se] = v;
            }
        } else {
            const float* srcr = toks + ((size_t)(b * LL + base + t0)) * DD;
#pragma unroll
            for (int p = 0; p < 4; ++p) {
                int t = p * 8 + st;
                const float* sp = srcr + (size_t)t * DD + se;
                float4 a0 = *(const float4*)sp;
                float4 a1 = *(const float4*)(sp + 4);
                bf16x8 v;
                v[0] = f2b(a0.x); v[1] = f2b(a0.y); v[2] = f2b(a0.z); v[3] = f2b(a0.w);
                v[4] = f2b(a1.x); v[5] = f2b(a1.y); v[6] = f2b(a1.z); v[7] = f2b(a1.w);
                *(bf16x8*)&Tr[t][se] = v;
                if (MODE == 1)
                    *(bf16x8*)(tcache + ((size_t)(b * LL + base + t0 + t)) * DD + se) = v;
            }
        }
        __syncthreads();
        f32x4 s0 = zer, s1 = zer;
        {
            int eb = w * 64 + 8 * qg;
            s0 = __builtin_amdgcn_mfma_f32_16x16x32_bf16(afr0, *(const bf16x8*)&Tr[hq][eb], s0, 0, 0, 0);
            s0 = __builtin_amdgcn_mfma_f32_16x16x32_bf16(afr1, *(const bf16x8*)&Tr[hq][eb + 32], s0, 0, 0, 0);
            s1 = __builtin_amdgcn_mfma_f32_16x16x32_bf16(afr0, *(const bf16x8*)&Tr[16 + hq][eb], s1, 0, 0, 0);
            s1 = __builtin_amdgcn_mfma_f32_16x16x32_bf16(afr1, *(const bf16x8*)&Tr[16 + hq][eb + 32], s1, 0, 0, 0);
        }
#pragma unroll
        for (int r = 0; r < 4; ++r) {
            Sred[w][qg * 4 + r][hq] = s0[r];
            Sred[w][qg * 4 + r][16 + hq] = s1[r];
        }
        __syncthreads();
        if (tid < 512) {
            int h = tid >> 5, t = tid & 31;
            float s = 0.f;
#pragma unroll
            for (int ww = 0; ww < 16; ++ww) s += Sred[ww][h][t];
            s = (s + sbh) * 0.125f;
            bool valid = (t0 + t) < nv;
            if (!valid) s = NEGINF;
            float tm = s;
#pragma unroll
            for (int off = 16; off; off >>= 1) tm = fmaxf(tm, __shfl_xor(tm, off, 32));
            float oldm = sm_m[h];
            float newm = fmaxf(oldm, tm);
            float pv = valid ? __expf(s - newm) : 0.f;
            float ps = pv;
#pragma unroll
            for (int off = 16; off; off >>= 1) ps += __shfl_xor(ps, off, 32);
            if (t == 0) {
                float corr = __expf(oldm - newm);
                sm_c[h] = corr;
                sm_m[h] = newm;
                sm_s[h] = sm_s[h] * corr + ps;
            }
            Pt[h][t] = f2b(pv);
        }
        __syncthreads();
        {
            float cr[4];
#pragma unroll
            for (int r = 0; r < 4; ++r) cr[r] = sm_c[qg * 4 + r];
            bf16x8 pafr;
            ushort4 pa0 = *(const ushort4*)&Pt[hq][8 * qg];
            ushort4 pa1 = *(const ushort4*)&Pt[hq][8 * qg + 4];
            pafr[0] = pa0.x; pafr[1] = pa0.y; pafr[2] = pa0.z; pafr[3] = pa0.w;
            pafr[4] = pa1.x; pafr[5] = pa1.y; pafr[6] = pa1.z; pafr[7] = pa1.w;
#pragma unroll
            for (int et = 0; et < 4; ++et) {
#pragma unroll
                for (int r = 0; r < 4; ++r) ctxacc[et][r] *= cr[r];
                bf16x8 bfr;
                int ec = w * 64 + et * 16 + hq;
#pragma unroll
                for (int i = 0; i < 8; ++i) bfr[i] = (short)Tr[8 * qg + i][ec];
                ctxacc[et] = __builtin_amdgcn_mfma_f32_16x16x32_bf16(pafr, bfr, ctxacc[et], 0, 0, 0);
            }
        }
        __syncthreads();
    }
    if (tid < HH) { m_p[pidx + tid] = sm_m[tid]; s_p[pidx + tid] = sm_s[tid]; }
#pragma unroll
    for (int et = 0; et < 4; ++et)
#pragma unroll
        for (int r = 0; r < 4; ++r) {
            int h = qg * 4 + r, e = w * 64 + et * 16 + hq;
            ctx_p[((size_t)pidx + h) * DD + e] = ctxacc[et][r];
        }
}

extern "C" void kernel_launch(void* const* d_in, const int* in_sizes, int n_in,
                              void* d_out, int out_size, void* d_ws, size_t ws_size,
                              hipStream_t stream) {
    const float* toks  = (const float*)d_in[0];
    const int*   lens  = (const int*)d_in[1];
    const float* qt    = (const float*)d_in[2];
    const float* Wq    = (const float*)d_in[3];
    const float* bq    = (const float*)d_in[4];
    const float* Wk    = (const float*)d_in[5];
    const float* bk    = (const float*)d_in[6];
    const float* Wv    = (const float*)d_in[7];
    const float* bv    = (const float*)d_in[8];
    const float* Wo    = (const float*)d_in[9];
    const float* bo    = (const float*)d_in[10];
    const float* gamma = (const float*)d_in[11];
    const float* beta  = (const float*)d_in[12];
    float* out = (float*)d_out;
    float* ws  = (float*)d_ws;

    // ws layout (float offsets)
    float* ctx_p = ws;                       // 4194304
    float* m_p   = ws + 4194304;             // 4096
    float* s_p   = ws + 4198400;             // 4096
    float* pvp   = ws + 4202496;             // 1048576 (KS*32*1024)
    float* op    = ws + 5251072;             // 1048576
    float* qp    = ws + 6299648;             // 1048576
    float* oraw  = ws + 7348224;             // 32768
    float* stats = ws + 7380992;             // 64
    float* qh    = ws + 7381056;             // 32768
    float* sbuf  = ws + 7413824;             // 512
    unsigned short* wk16 = (unsigned short*)(ws + 7414336);  // 524288 u16 = 262144 f
    const size_t base_floats = 7676480;
    unsigned short* tcache = (unsigned short*)(ws + base_floats);
    const size_t need_cache = base_floats * 4 + (size_t)BB * LL * DD * 2;
    const bool use_cache = (ws_size >= need_cache);

    float* g0 = oraw;   // reuse (prologue only)

    // prologue: qh = qt @ Wq0 + bq0 (broadcast over b), then wk for layer 0
    k_bcast<<<128, 256, 0, stream>>>(qt, g0);
    k_gemv<0><<<512, 256, 0, stream>>>(g0, nullptr, nullptr, nullptr, nullptr,
            nullptr, nullptr, nullptr, nullptr, Wq, qp);
    k_comb_bias<<<128, 256, 0, stream>>>(qp, bq, qh);
    k_wk<<<256, 256, 0, stream>>>(qh, Wk, bk, wk16, sbuf);

    for (int i = 0; i < NL; ++i) {
        if (use_cache) {
            if (i == 0)
                k_attn<1><<<256, 1024, 0, stream>>>(toks, tcache, lens, wk16,
                        sbuf, ctx_p, m_p, s_p);
            else
                k_attn<2><<<256, 1024, 0, stream>>>(toks, tcache, lens, wk16,
                        sbuf, ctx_p, m_p, s_p);
        } else {
            k_attn<0><<<256, 1024, 0, stream>>>(toks, tcache, lens, wk16,
                    sbuf, ctx_p, m_p, s_p);
        }
        const float* Wv_i = Wv + (size_t)i * DD * DD;
        const float* Wo_i = Wo + (size_t)i * DD * DD;
        // pv partials: (chunk-combined ctx) @ Wv
        k_gemv<3><<<512, 256, 0, stream>>>(nullptr, nullptr, nullptr, nullptr,
                nullptr, nullptr, ctx_p, m_p, s_p, Wv_i, pvp);
        // o partials: (sum pv + bv) @ Wo
        k_gemv<2><<<512, 256, 0, stream>>>(nullptr, nullptr, nullptr, nullptr,
                pvp, bv + i * DD, nullptr, nullptr, nullptr, Wo_i, op);
        // combine + bo -> oraw, LN stats
        k_stats<<<32, 256, 0, stream>>>(op, bo + i * DD, oraw, stats);
        if (i == NL - 1) {
            k_final<<<128, 256, 0, stream>>>(oraw, stats, gamma + i * DD,
                    beta + i * DD, out);
        } else {
            // q_{i+1} = LN(oraw) @ Wq_{i+1} + bq_{i+1}; then wk for next layer
            k_gemv<1><<<512, 256, 0, stream>>>(oraw, stats, gamma + i * DD,
                    beta + i * DD, nullptr, nullptr, nullptr, nullptr, nullptr,
                    Wq + (size_t)(i + 1) * DD * DD, qp);
            k_comb_bias<<<128, 256, 0, stream>>>(qp, bq + (i + 1) * DD, qh);
            k_wk<<<256, 256, 0, stream>>>(qh, Wk + (size_t)(i + 1) * DD * DD,
                    bk + (i + 1) * DD, wk16, sbuf);
        }
    }
}